// Round 14
// baseline (47.548 us; speedup 1.0000x reference)
//
#include <hip/hip_runtime.h>
#include <math.h>

#define NIMG 24        // B*C = 8*3
#define H    256
#define W    256
#define NPIX (H * W)
#define CPB  8                    // columns per block
#define SLICES (W / CPB)          // 32 blocks per image
#define NBLK (NIMG * SLICES)      // 768
#define LDP  9                    // padded LDS row stride (2-way banks, free)
#define BIGI 1000000

// ---------------------------------------------------------------------------
// ONE self-sufficient compute kernel — ZERO cross-block communication
// (r7/r12/r13 lesson, 3x replicated: device-scope fences/atomics cost tens
// of us; r9 calibration: node overhead <1us so a tiny finalize node is free).
//
// Block = (img, 8-col group), 768 blocks x 256 thr (3/CU balanced; r9's
// version of this idea failed at 192 blocks/15% occupancy with the 26-step
// wave-scan — fixed by 3x occupancy and the ballot O(1) EDT, r11-validated
// bit-exact). Each block recomputes the row EDT for ALL 256 rows of its
// image (4 waves x 64 rows), keeping only its 8-column f slice in LDS; the
// 32x-redundant tgt reads are L2-resident via the XCD-aware mapping
// img = 3*(bid&7) + (bid>>8)  (each XCD's L2 holds its 3 images, 1.5MB).
// Full-image scan also gives the EXACT mask-empty flag (no extra pass).
//
// Capped rows (no class change): g = 1e6 exactly; reference's capped value
// differs (1e6 - col) but provably never wins the pass-2 min when the image
// is nonempty (any finite g <= 256 beats ~1e12), and the empty-image case
// is handled by the flag -> output identical.
//
// Phase B: window-bounded exact min-plus (minimizer satisfies |i-k|<=g[i]
// since k=i gives g[i]^2; all finite terms exact fp32 ints -> bitwise equal
// to reference's full scan), + sigmoid(pred)*d, fixed-order double
// reduction -> partials[bid]. Finalize node sums 768 in fixed order.
// ---------------------------------------------------------------------------
__global__ __launch_bounds__(256)
void boundary_main_kernel(const int* __restrict__ tgt,
                          const float* __restrict__ pred,
                          double* __restrict__ partials) {
    const int bid  = blockIdx.x;
    const int img  = ((bid & 7) * 3) + (bid >> 8);   // XCD-local image
    const int grp  = (bid >> 3) & 31;
    const int j0   = grp << 3;
    const int t    = threadIdx.x;
    const int lane = t & 63;
    const int wid  = t >> 6;

    __shared__ float sf[H][LDP];      // 9.2 KB f slice
    __shared__ double wsum[4];
    __shared__ int nonempty;
    if (t == 0) nonempty = 0;
    __syncthreads();

    // ---------- phase A: ballot row EDT, all 256 rows, keep 8-col slice ----
    const int  c0   = lane << 2;
    const int  cb   = c0 - j0;        // column within tile, if mine
    const bool mine = (cb >= 0) && (cb < CPB);
    const int  ibase = img << 16;
    int anynz = 0;

    for (int rr = 0; rr < 64; ++rr) {
        const int row = (wid << 6) + rr;
        const int4 tv = ((const int4*)(tgt + ibase + (row << 8)))[lane];
        anynz |= tv.x | tv.y | tv.z | tv.w;

        // class-change flags (global index 0 has no predecessor -> false)
        const int prevw = __shfl_up(tv.w, 1, 64);
        const bool ch0 = (lane > 0) && ((tv.x != 0) != (prevw != 0));
        const bool ch1 = (tv.y != 0) != (tv.x != 0);
        const bool ch2 = (tv.z != 0) != (tv.y != 0);
        const bool ch3 = (tv.w != 0) != (tv.z != 0);

        const int a0 = ch0 ? c0     : -BIGI;
        const int a1 = ch1 ? c0 + 1 : a0;
        const int a2 = ch2 ? c0 + 2 : a1;
        const int a3 = ch3 ? c0 + 3 : a2;     // lane's last change (or -BIGI)
        const int rb3 = ch3 ? c0 + 3 : BIGI;
        const int rb2 = ch2 ? c0 + 2 : rb3;
        const int rb1 = ch1 ? c0 + 1 : rb2;
        const int rb0 = ch0 ? c0     : rb1;   // lane's first change (or BIGI)

        const unsigned long long mask = __ballot(ch0 | ch1 | ch2 | ch3);
        const unsigned long long lowm = mask & ((1ULL << lane) - 1ULL);
        const unsigned long long him  = (lane < 63) ? (mask >> (lane + 1)) : 0ULL;

        const int plane = 63 - __builtin_clzll(lowm | 1ULL);
        const int sh_a  = __shfl(a3, plane & 63, 64);
        const int ex    = (lowm != 0ULL) ? sh_a : -BIGI;   // last change < c0

        const int qlane = lane + 1 +
            (int)__builtin_ctzll(him | 0x8000000000000000ULL);
        const int sh_r  = __shfl(rb0, qlane & 63, 64);
        const int exr   = (him != 0ULL) ? sh_r : BIGI;     // first change > c3

        if (mine) {
            const int s0 = (ex > a0) ? ex : a0;
            const int s1 = (ex > a1) ? ex : a1;
            const int s2 = (ex > a2) ? ex : a2;
            const int s3 = (ex > a3) ? ex : a3;
            const int n0 = (rb1 < exr) ? rb1 : exr;
            const int n1 = (rb2 < exr) ? rb2 : exr;
            const int n2 = (rb3 < exr) ? rb3 : exr;
            const int n3 = exr;

            auto gcalc = [](int c, int ss, int nn) -> int {
                int dp = c - ss + 1;
                int dn = nn - c;
                int g = dp < dn ? dp : dn;
                return g < BIGI ? g : BIGI;
            };
            const float g0 = (float)gcalc(c0,     s0, n0);
            const float g1 = (float)gcalc(c0 + 1, s1, n1);
            const float g2 = (float)gcalc(c0 + 2, s2, n2);
            const float g3 = (float)gcalc(c0 + 3, s3, n3);

            sf[row][cb]     = (tv.x != 0) ? g0 : -g0;
            sf[row][cb + 1] = (tv.y != 0) ? g1 : -g1;
            sf[row][cb + 2] = (tv.z != 0) ? g2 : -g2;
            sf[row][cb + 3] = (tv.w != 0) ? g3 : -g3;
        }
    }
    if (__any(anynz != 0)) {
        if (lane == 0) nonempty = 1;  // benign race, all write 1
    }
    __syncthreads();
    const int flag = nonempty;        // exact: mask.sum() != 0 (full image)

    // ---------- phase B: window-bounded exact min-plus ----------
    const int c  = t & 7;             // own column within tile
    const int r0 = (t >> 3) << 3;     // own 8-row band
    double acc = 0.0;
#pragma unroll
    for (int ii = 0; ii < 8; ++ii) {
        const int i = r0 + ii;
        const float fv = sf[i][c];
        const bool  m  = fv > 0.0f;   // sign(f) = pixel polarity
        const float sgn = m ? 1.0f : -1.0f;
        const float gi = fabsf(fv);
        const int  gii = (int)gi;
        int lo = i - gii; lo = lo > 0 ? lo : 0;
        int hi = i + gii; hi = hi < (H - 1) ? hi : (H - 1);

        float dm = 3.0e38f;
        float dk = (float)(i - lo);
        for (int k = lo; k <= hi; ++k) {
            const float g = fmaxf(sgn * sf[k][c], 0.0f);   // needed polarity
            dm = fminf(dm, g * g + dk * dk);
            dk -= 1.0f;
        }

        float d = m ? sqrtf(dm) : -sqrtf(dm);
        if (!flag) d = 0.0f;
        const float p = pred[ibase + (i << 8) + j0 + c];
        const float sig = 1.0f / (1.0f + expf(-p));
        acc += (double)sig * (double)d;
    }

    // wave reduce (double, fixed order), 4 wave sums -> block partial
#pragma unroll
    for (int off = 32; off > 0; off >>= 1) acc += __shfl_down(acc, off, 64);
    if (lane == 0) wsum[wid] = acc;
    __syncthreads();
    if (t == 0) partials[bid] = (wsum[0] + wsum[1]) + (wsum[2] + wsum[3]);
}

// ---------------------------------------------------------------------------
// Finalize: deterministic fixed-order sum of 768 partials -> mean -> fp32
// (separate node — r9 calibration: <1us overhead; no fences/atomics needed)
// ---------------------------------------------------------------------------
__global__ void finalize_kernel(const double* __restrict__ partials,
                                float* __restrict__ out) {
    const int t = threadIdx.x;        // 64 threads
    double a = 0.0;
#pragma unroll
    for (int s = 0; s < NBLK / 64; ++s) a += partials[t + (s << 6)];
#pragma unroll
    for (int off = 32; off > 0; off >>= 1) a += __shfl_down(a, off, 64);
    if (t == 0) out[0] = (float)(a / (double)(NIMG * NPIX));
}

extern "C" void kernel_launch(void* const* d_in, const int* in_sizes, int n_in,
                              void* d_out, int out_size, void* d_ws, size_t ws_size,
                              hipStream_t stream) {
    const float* pred = (const float*)d_in[0];
    const int*   tgt  = (const int*)d_in[1];
    float* out = (float*)d_out;

    double* partials = (double*)d_ws; // 768 * 8 B

    boundary_main_kernel<<<NBLK, 256, 0, stream>>>(tgt, pred, partials);
    finalize_kernel<<<1, 64, 0, stream>>>(partials, out);
}

// Round 15
// 24.172 us; speedup vs baseline: 1.9671x; 1.9671x over previous
//
#include <hip/hip_runtime.h>
#include <math.h>

#define NIMG 24        // B*C = 8*3
#define H    256
#define W    256
#define NPIX (H * W)
#define NROWS (NIMG * H)          // 6144
#define CPB  32                   // columns per K2 tile
#define NBLK2 (NIMG * (W / CPB))  // 192
#define LDP2 33                   // padded LDS row stride (floats)
#define BIGI 1000000
#define CAPS 1024                 // int16 sentinel for capped g (=1e6)

// ---------------------------------------------------------------------------
// K1: 96 blocks x 1024 thr (16 waves x 4 rows = 6144 rows). Ballot-based
// O(1) row EDT (r11-validated bit-exact), int16 output (r13-validated:
// +-g in [1,256], sentinel +-1024 for capped rows). FEW FAT BLOCKS —
// r15 theory: r11's hidden ~15us is the 2305-block dispatch walk
// (~10ns/block); this pipeline issues 289 total.
// ---------------------------------------------------------------------------
__global__ __launch_bounds__(1024)
void edt_rows_kernel(const int* __restrict__ tgt,
                     short* __restrict__ f) {
    const int lane = threadIdx.x & 63;
    const int wid  = threadIdx.x >> 6;
    const int gw   = blockIdx.x * 16 + wid;   // 0..1535
    const int c0   = lane << 2;

#pragma unroll
    for (int s = 0; s < 4; ++s) {
        const int row = (gw << 2) + s;        // global row 0..6143
        const int4 tv = ((const int4*)(tgt + (row << 8)))[lane];

        // class-change flags (index 0 has no predecessor -> false)
        const int prevw = __shfl_up(tv.w, 1, 64);
        const bool ch0 = (lane > 0) && ((tv.x != 0) != (prevw != 0));
        const bool ch1 = (tv.y != 0) != (tv.x != 0);
        const bool ch2 = (tv.z != 0) != (tv.y != 0);
        const bool ch3 = (tv.w != 0) != (tv.z != 0);

        const int a0 = ch0 ? c0     : -BIGI;
        const int a1 = ch1 ? c0 + 1 : a0;
        const int a2 = ch2 ? c0 + 2 : a1;
        const int a3 = ch3 ? c0 + 3 : a2;     // lane's last change (or -BIGI)
        const int rb3 = ch3 ? c0 + 3 : BIGI;
        const int rb2 = ch2 ? c0 + 2 : rb3;
        const int rb1 = ch1 ? c0 + 1 : rb2;
        const int rb0 = ch0 ? c0     : rb1;   // lane's first change (or BIGI)

        const unsigned long long mask = __ballot(ch0 | ch1 | ch2 | ch3);
        const unsigned long long lowm = mask & ((1ULL << lane) - 1ULL);
        const unsigned long long him  = (lane < 63) ? (mask >> (lane + 1)) : 0ULL;

        const int plane = 63 - __builtin_clzll(lowm | 1ULL);
        const int sh_a  = __shfl(a3, plane & 63, 64);
        const int ex    = (lowm != 0ULL) ? sh_a : -BIGI;   // last change < c0

        const int qlane = lane + 1 +
            (int)__builtin_ctzll(him | 0x8000000000000000ULL);
        const int sh_r  = __shfl(rb0, qlane & 63, 64);
        const int exr   = (him != 0ULL) ? sh_r : BIGI;     // first change > c3

        const int s0 = (ex > a0) ? ex : a0;
        const int s1 = (ex > a1) ? ex : a1;
        const int s2 = (ex > a2) ? ex : a2;
        const int s3 = (ex > a3) ? ex : a3;
        const int n0 = (rb1 < exr) ? rb1 : exr;
        const int n1 = (rb2 < exr) ? rb2 : exr;
        const int n2 = (rb3 < exr) ? rb3 : exr;
        const int n3 = exr;

        auto gcalc = [](int c, int ss, int nn) -> int {
            int dp = c - ss + 1;
            int dn = nn - c;
            int g = dp < dn ? dp : dn;
            return (g < BIGI) ? g : CAPS;     // encode cap as sentinel
        };
        const int g0 = gcalc(c0,     s0, n0);
        const int g1 = gcalc(c0 + 1, s1, n1);
        const int g2 = gcalc(c0 + 2, s2, n2);
        const int g3 = gcalc(c0 + 3, s3, n3);

        short4 o;
        o.x = (short)((tv.x != 0) ? g0 : -g0);
        o.y = (short)((tv.y != 0) ? g1 : -g1);
        o.z = (short)((tv.z != 0) ? g2 : -g2);
        o.w = (short)((tv.w != 0) ? g3 : -g3);
        ((short4*)(f + (row << 8)))[lane] = o;
    }
}

// ---------------------------------------------------------------------------
// K2: 192 blocks x 1024 thr, tile = (img, 32-col group). Stage one int4
// (8 shorts) per thread, decode (sentinel +-1024 -> +-1e6f; r13-validated —
// capped terms round identically in the min) into padded LDS. Empty-mask
// flag from cap markers (cap = row-global property: all staged == -1024
// <=> every row has no foreground <=> mask empty; r10/r11-validated).
// Window-bounded exact min-plus (minimizer satisfies |i-k| <= g[i] since
// k=i gives g[i]^2; all finite terms exact fp32 ints -> bitwise equal to
// reference). 8 px/thread, 16-wave fixed-order double reduction.
// No cross-block sync of any kind (r7/r12/r13 lesson, 3x replicated).
// ---------------------------------------------------------------------------
__global__ __launch_bounds__(1024)
void edt_cols_kernel(const short* __restrict__ f,
                     const float* __restrict__ pred,
                     double* __restrict__ partials) {
    const int bid  = blockIdx.x;          // img*8 + grp
    const int img  = bid >> 3;
    const int j0   = (bid & 7) << 5;
    const int t    = threadIdx.x;
    const int lane = t & 63;
    const int wid  = t >> 6;

    __shared__ float sf[H][LDP2];         // 33.8 KB decoded f tile
    __shared__ double wsum[16];
    __shared__ int nonempty;
    if (t == 0) nonempty = 0;
    __syncthreads();

    // stage: thread t owns (row = t>>2, 8-col chunk q = (t&3)*8)
    {
        const int row = t >> 2;
        const int q   = (t & 3) << 3;
        const int4 rv = *(const int4*)(f + (img << 16) + (row << 8) + j0 + q);
        const short* sv = (const short*)&rv;
        bool ne = false;
#pragma unroll
        for (int j = 0; j < 8; ++j) {
            const int v = sv[j];
            ne = ne || (v != -CAPS);
            float g = (float)v;
            if (v == CAPS)  g =  1.0e6f;
            if (v == -CAPS) g = -1.0e6f;
            sf[row][q + j] = g;
        }
        if (ne) nonempty = 1;             // benign race, all write 1
    }
    __syncthreads();
    const int flag = nonempty;            // exact: mask.sum() != 0

    // phase B: window-bounded exact min-plus, 8 pixels per thread
    const int c  = t & 31;                // own column within tile
    const int r0 = (t >> 5) << 3;         // own 8-row band
    double acc = 0.0;
#pragma unroll
    for (int ii = 0; ii < 8; ++ii) {
        const int i = r0 + ii;
        const float fv = sf[i][c];
        const bool  m  = fv > 0.0f;       // sign(f) = pixel polarity
        const float sgn = m ? 1.0f : -1.0f;
        const float gi = fabsf(fv);
        const int  gii = (int)gi;
        int lo = i - gii; lo = lo > 0 ? lo : 0;
        int hi = i + gii; hi = hi < (H - 1) ? hi : (H - 1);

        float dm = 3.0e38f;
        float dk = (float)(i - lo);
        for (int k = lo; k <= hi; ++k) {
            const float g = fmaxf(sgn * sf[k][c], 0.0f);  // needed polarity
            dm = fminf(dm, g * g + dk * dk);
            dk -= 1.0f;
        }

        float d = m ? sqrtf(dm) : -sqrtf(dm);
        if (!flag) d = 0.0f;
        const float p = pred[(img << 16) + (i << 8) + j0 + c];
        const float sig = 1.0f / (1.0f + expf(-p));
        acc += (double)sig * (double)d;
    }

    // wave reduce (double, fixed order), 16 wave sums -> block partial
#pragma unroll
    for (int off = 32; off > 0; off >>= 1) acc += __shfl_down(acc, off, 64);
    if (lane == 0) wsum[wid] = acc;
    __syncthreads();
    if (t == 0) {
        double s = 0.0;
#pragma unroll
        for (int w = 0; w < 16; ++w) s += wsum[w];
        partials[bid] = s;
    }
}

// ---------------------------------------------------------------------------
// K3: deterministic fixed-order sum of 192 partials -> mean -> fp32
// ---------------------------------------------------------------------------
__global__ void finalize_kernel(const double* __restrict__ partials,
                                float* __restrict__ out) {
    const int t = threadIdx.x;            // 64 threads
    double a = partials[t] + partials[t + 64] + partials[t + 128];
#pragma unroll
    for (int off = 32; off > 0; off >>= 1) a += __shfl_down(a, off, 64);
    if (t == 0) out[0] = (float)(a / (double)(NIMG * NPIX));
}

extern "C" void kernel_launch(void* const* d_in, const int* in_sizes, int n_in,
                              void* d_out, int out_size, void* d_ws, size_t ws_size,
                              hipStream_t stream) {
    const float* pred = (const float*)d_in[0];
    const int*   tgt  = (const int*)d_in[1];
    float* out = (float*)d_out;

    char* ws = (char*)d_ws;
    const size_t fbytes = (size_t)NIMG * NPIX * sizeof(short);   // 3,145,728 B
    short*  fbuf     = (short*)(ws);
    double* partials = (double*)(ws + fbytes);                   // 192 * 8 B

    edt_rows_kernel<<<NROWS / 64, 1024, 0, stream>>>(tgt, fbuf);       // 96
    edt_cols_kernel<<<NBLK2, 1024, 0, stream>>>(fbuf, pred, partials); // 192
    finalize_kernel<<<1, 64, 0, stream>>>(partials, out);              // 1
}

// Round 16
// 22.809 us; speedup vs baseline: 2.0846x; 1.0598x over previous
//
#include <hip/hip_runtime.h>
#include <math.h>

#define NIMG 24        // B*C = 8*3
#define H    256
#define W    256
#define NPIX (H * W)
#define NROWS (NIMG * H)          // 6144
#define CPB  32                   // columns per K2 tile
#define NBLK2 (NIMG * (W / CPB))  // 192
#define LDP2 33                   // padded LDS row stride (floats)
#define BIGI 1000000
#define CAPS 1024                 // int16 sentinel for capped g (=1e6)

// ---------------------------------------------------------------------------
// K1: 192 blocks x 512 thr (8 waves x 4 rows = 6144 rows) — r15 lesson: the
// 96-block version used only 96 CUs (BW-starved); 192 blocks doubles the
// active CUs for the same 9.4 MB of traffic. Ballot-based O(1) row EDT
// (r11-validated bit-exact), int16 output (r13-validated: +-g in [1,256],
// sentinel +-1024 for capped rows). Thread (0,0) zeroes out[0] — published
// to K2's atomics by the node boundary (no fence needed).
// ---------------------------------------------------------------------------
__global__ __launch_bounds__(512)
void edt_rows_kernel(const int* __restrict__ tgt,
                     short* __restrict__ f,
                     float* __restrict__ out) {
    if (blockIdx.x == 0 && threadIdx.x == 0) out[0] = 0.0f;

    const int lane = threadIdx.x & 63;
    const int wid  = threadIdx.x >> 6;        // 0..7
    const int gw   = blockIdx.x * 8 + wid;    // 0..1535
    const int c0   = lane << 2;

#pragma unroll
    for (int s = 0; s < 4; ++s) {
        const int row = (gw << 2) + s;        // global row 0..6143
        const int4 tv = ((const int4*)(tgt + (row << 8)))[lane];

        // class-change flags (index 0 has no predecessor -> false)
        const int prevw = __shfl_up(tv.w, 1, 64);
        const bool ch0 = (lane > 0) && ((tv.x != 0) != (prevw != 0));
        const bool ch1 = (tv.y != 0) != (tv.x != 0);
        const bool ch2 = (tv.z != 0) != (tv.y != 0);
        const bool ch3 = (tv.w != 0) != (tv.z != 0);

        const int a0 = ch0 ? c0     : -BIGI;
        const int a1 = ch1 ? c0 + 1 : a0;
        const int a2 = ch2 ? c0 + 2 : a1;
        const int a3 = ch3 ? c0 + 3 : a2;     // lane's last change (or -BIGI)
        const int rb3 = ch3 ? c0 + 3 : BIGI;
        const int rb2 = ch2 ? c0 + 2 : rb3;
        const int rb1 = ch1 ? c0 + 1 : rb2;
        const int rb0 = ch0 ? c0     : rb1;   // lane's first change (or BIGI)

        const unsigned long long mask = __ballot(ch0 | ch1 | ch2 | ch3);
        const unsigned long long lowm = mask & ((1ULL << lane) - 1ULL);
        const unsigned long long him  = (lane < 63) ? (mask >> (lane + 1)) : 0ULL;

        const int plane = 63 - __builtin_clzll(lowm | 1ULL);
        const int sh_a  = __shfl(a3, plane & 63, 64);
        const int ex    = (lowm != 0ULL) ? sh_a : -BIGI;   // last change < c0

        const int qlane = lane + 1 +
            (int)__builtin_ctzll(him | 0x8000000000000000ULL);
        const int sh_r  = __shfl(rb0, qlane & 63, 64);
        const int exr   = (him != 0ULL) ? sh_r : BIGI;     // first change > c3

        const int s0 = (ex > a0) ? ex : a0;
        const int s1 = (ex > a1) ? ex : a1;
        const int s2 = (ex > a2) ? ex : a2;
        const int s3 = (ex > a3) ? ex : a3;
        const int n0 = (rb1 < exr) ? rb1 : exr;
        const int n1 = (rb2 < exr) ? rb2 : exr;
        const int n2 = (rb3 < exr) ? rb3 : exr;
        const int n3 = exr;

        auto gcalc = [](int c, int ss, int nn) -> int {
            int dp = c - ss + 1;
            int dn = nn - c;
            int g = dp < dn ? dp : dn;
            return (g < BIGI) ? g : CAPS;     // encode cap as sentinel
        };
        const int g0 = gcalc(c0,     s0, n0);
        const int g1 = gcalc(c0 + 1, s1, n1);
        const int g2 = gcalc(c0 + 2, s2, n2);
        const int g3 = gcalc(c0 + 3, s3, n3);

        short4 o;
        o.x = (short)((tv.x != 0) ? g0 : -g0);
        o.y = (short)((tv.y != 0) ? g1 : -g1);
        o.z = (short)((tv.z != 0) ? g2 : -g2);
        o.w = (short)((tv.w != 0) ? g3 : -g3);
        ((short4*)(f + (row << 8)))[lane] = o;
    }
}

// ---------------------------------------------------------------------------
// K2: 192 blocks x 1024 thr, tile = (img, 32-col group). r15-validated
// bit-exact math throughout. Stage one int4 (8 shorts) per thread, decode
// (sentinel +-1024 -> +-1e6f) into padded LDS. Empty-mask flag from cap
// markers. Window-bounded exact min-plus (minimizer satisfies |i-k| <= g[i]
// since k=i gives g[i]^2; all finite terms exact fp32 ints -> bitwise equal
// to reference). 8 px/thread, 16-wave fixed-order double reduction.
// FINALIZE FUSED (r16): block partial, pre-divided by N in double and
// converted to fp32, is atomicAdd'ed onto out[0]. Consumer-side bare atomic
// RMW — NO fences/tickets/spins (what r12/r13 falsified was the
// release-acquire discipline, not atomics per se). 192 same-line atomics,
// pre-staggered by block completion (r3's pathological case was 6144).
// Rounding budget: 192 fp32 adds of ~3e-6 terms -> error ~1e-8 << 1.2e-5.
// ---------------------------------------------------------------------------
__global__ __launch_bounds__(1024)
void edt_cols_kernel(const short* __restrict__ f,
                     const float* __restrict__ pred,
                     float* __restrict__ out) {
    const int bid  = blockIdx.x;          // img*8 + grp
    const int img  = bid >> 3;
    const int j0   = (bid & 7) << 5;
    const int t    = threadIdx.x;
    const int lane = t & 63;
    const int wid  = t >> 6;

    __shared__ float sf[H][LDP2];         // 33.8 KB decoded f tile
    __shared__ double wsum[16];
    __shared__ int nonempty;
    if (t == 0) nonempty = 0;
    __syncthreads();

    // stage: thread t owns (row = t>>2, 8-col chunk q = (t&3)*8)
    {
        const int row = t >> 2;
        const int q   = (t & 3) << 3;
        const int4 rv = *(const int4*)(f + (img << 16) + (row << 8) + j0 + q);
        const short* sv = (const short*)&rv;
        bool ne = false;
#pragma unroll
        for (int j = 0; j < 8; ++j) {
            const int v = sv[j];
            ne = ne || (v != -CAPS);
            float g = (float)v;
            if (v == CAPS)  g =  1.0e6f;
            if (v == -CAPS) g = -1.0e6f;
            sf[row][q + j] = g;
        }
        if (ne) nonempty = 1;             // benign race, all write 1
    }
    __syncthreads();
    const int flag = nonempty;            // exact: mask.sum() != 0

    // phase B: window-bounded exact min-plus, 8 pixels per thread
    const int c  = t & 31;                // own column within tile
    const int r0 = (t >> 5) << 3;         // own 8-row band
    double acc = 0.0;
#pragma unroll
    for (int ii = 0; ii < 8; ++ii) {
        const int i = r0 + ii;
        const float fv = sf[i][c];
        const bool  m  = fv > 0.0f;       // sign(f) = pixel polarity
        const float sgn = m ? 1.0f : -1.0f;
        const float gi = fabsf(fv);
        const int  gii = (int)gi;
        int lo = i - gii; lo = lo > 0 ? lo : 0;
        int hi = i + gii; hi = hi < (H - 1) ? hi : (H - 1);

        float dm = 3.0e38f;
        float dk = (float)(i - lo);
        for (int k = lo; k <= hi; ++k) {
            const float g = fmaxf(sgn * sf[k][c], 0.0f);  // needed polarity
            dm = fminf(dm, g * g + dk * dk);
            dk -= 1.0f;
        }

        float d = m ? sqrtf(dm) : -sqrtf(dm);
        if (!flag) d = 0.0f;
        const float p = pred[(img << 16) + (i << 8) + j0 + c];
        const float sig = 1.0f / (1.0f + expf(-p));
        acc += (double)sig * (double)d;
    }

    // wave reduce (double, fixed order), 16 wave sums -> block partial
#pragma unroll
    for (int off = 32; off > 0; off >>= 1) acc += __shfl_down(acc, off, 64);
    if (lane == 0) wsum[wid] = acc;
    __syncthreads();
    if (t == 0) {
        double s = 0.0;
#pragma unroll
        for (int w = 0; w < 16; ++w) s += wsum[w];
        atomicAdd(out, (float)(s * (1.0 / (double)(NIMG * NPIX))));
    }
}

extern "C" void kernel_launch(void* const* d_in, const int* in_sizes, int n_in,
                              void* d_out, int out_size, void* d_ws, size_t ws_size,
                              hipStream_t stream) {
    const float* pred = (const float*)d_in[0];
    const int*   tgt  = (const int*)d_in[1];
    float* out = (float*)d_out;

    short* fbuf = (short*)d_ws;           // 3,145,728 B intermediate

    edt_rows_kernel<<<192, 512, 0, stream>>>(tgt, fbuf, out);
    edt_cols_kernel<<<NBLK2, 1024, 0, stream>>>(fbuf, pred, out);
}